// Round 8
// baseline (270.871 us; speedup 1.0000x reference)
//
#include <hip/hip_runtime.h>
#include <hip/hip_bf16.h>

// Problem constants: B=2, S=2048, D=2048, H=32, KVH=8, HD=64, N_REP=4
#define BB 2
#define SS 2048
#define DD 2048
#define HH 32
#define KVH 8
#define HD 64
#define QKV_LD 3072   // Q(2048) | K(512) | V(512)

typedef unsigned short u16;
typedef unsigned int u32;
typedef __attribute__((ext_vector_type(8))) short s16x8;   // bf16x8 MFMA fragment (4 VGPRs)
typedef __attribute__((ext_vector_type(4))) float f32x4;   // MFMA accumulator
typedef __attribute__((ext_vector_type(4))) u16 u16x4;
typedef __attribute__((ext_vector_type(2))) u32 u32x2;

#define MFMA(a, b, c) __builtin_amdgcn_mfma_f32_16x16x32_bf16((a), (b), (c), 0, 0, 0)

__device__ __forceinline__ u16 f2bf(float f) {
  union { float f; u32 u; } x; x.f = f;
  u32 r = x.u + 0x7fffu + ((x.u >> 16) & 1u);  // round-to-nearest-even
  return (u16)(r >> 16);
}
__device__ __forceinline__ float bf2f(u32 u) {
  union { u32 u; float f; } x; x.u = u << 16;
  return x.f;
}
// HW packed f32x2 -> bf16x2 (RTNE), lo=a, hi=b
__device__ __forceinline__ u32 cvtpk(float a, float b) {
  u32 r;
  asm("v_cvt_pk_bf16_f32 %0, %1, %2" : "=v"(r) : "v"(a), "v"(b));
  return r;
}

// async global->LDS, 16B per lane. dest must be (wave-uniform base + lane*16).
__device__ __forceinline__ void gload16(const void* g, void* l) {
  __builtin_amdgcn_global_load_lds((const __attribute__((address_space(1))) unsigned int*)g,
                                   (__attribute__((address_space(3))) unsigned int*)l, 16, 0, 0);
}

// Read one bf16x8 MFMA fragment from a [rows][64] bf16 LDS tile with the
// G4 XOR swizzle (16B block index ^= row&7). c = 16B-block index (k/8).
__device__ __forceinline__ s16x8 lds_frag(const u16* base, int row, int c) {
  return *(const s16x8*)(base + (row << 6) + (((c ^ (row & 7)) << 3)));
}

// ---------------------------------------------------------------------------
// zero fp32 buffer, 4 elems/thread, exact grid
__global__ void zero_f4(float* __restrict__ p) {
  int i = blockIdx.x * 256 + threadIdx.x;
  ((float4*)p)[i] = make_float4(0.f, 0.f, 0.f, 0.f);
}

// cast fp32 -> bf16, 4 elems/thread, exact grid
__global__ void cast_bf(const float* __restrict__ s, u16* __restrict__ d) {
  int i = blockIdx.x * 256 + threadIdx.x;
  float4 v = ((const float4*)s)[i];
  u16x4 o;
  o[0] = f2bf(v.x); o[1] = f2bf(v.y); o[2] = f2bf(v.z); o[3] = f2bf(v.w);
  ((u16x4*)d)[i] = o;
}

// transpose-cast: dst[c*dld + r] = bf16(src[r*scols + c]); grid (scols/32, srows/32), block (32,8)
__global__ void tcast(const float* __restrict__ src, int scols, u16* __restrict__ dst, int dld) {
  __shared__ float tt[32][33];
  int c0 = blockIdx.x << 5, r0 = blockIdx.y << 5;
  int tx = threadIdx.x, ty = threadIdx.y;
#pragma unroll
  for (int j = 0; j < 4; ++j)
    tt[ty + j * 8][tx] = src[(size_t)(r0 + ty + j * 8) * scols + c0 + tx];
  __syncthreads();
#pragma unroll
  for (int j = 0; j < 4; ++j)
    dst[(size_t)(c0 + ty + j * 8) * dld + r0 + tx] = f2bf(tt[tx][ty + j * 8]);
}

// RoPE in-place on Q cols [0,2048) and K cols [2048,2560) of qkv [4096][3072].
// Q additionally pre-scaled by 1/sqrt(HD)*log2(e) (folded attention scale).
__global__ void rope_k(u16* __restrict__ qkv, const float* __restrict__ fc, const float* __restrict__ fs) {
  const float SCLQ = 0.125f * 1.44269504f;
  int idx = blockIdx.x * 256 + threadIdx.x;          // 4096*1280 total
  int row = idx / 1280;
  int p = idx - row * 1280;
  int s = row & (SS - 1);
  int col, i;
  float sc;
  if (p < 1024) { col = p << 1; i = p & 31; sc = SCLQ; }
  else { int pk = p - 1024; col = 2048 + (pk << 1); i = pk & 31; sc = 1.0f; }
  size_t base = (size_t)row * QKV_LD + col;
  u32 v = *(const u32*)(qkv + base);
  float t1 = bf2f(v & 0xffffu), t2 = bf2f(v >> 16);
  float c = fc[s * 32 + i], sn = fs[s * 32 + i];
  float r1 = (t1 * c - t2 * sn) * sc;
  float r2 = (t1 * sn + t2 * c) * sc;
  *(u32*)(qkv + base) = (u32)f2bf(r1) | ((u32)f2bf(r2) << 16);
}

// V part of qkv (cols [2560,3072)) -> vt[((b*8+g)*64 + d)*2048 + s]
__global__ void transpose_v(const u16* __restrict__ qkv, u16* __restrict__ vt) {
  __shared__ u16 tt[32][33];
  int c0 = blockIdx.x << 5, r0 = blockIdx.y << 5;   // c0: V col, r0: b*S+s row
  int tx = threadIdx.x, ty = threadIdx.y;
#pragma unroll
  for (int j = 0; j < 4; ++j)
    tt[ty + j * 8][tx] = qkv[(size_t)(r0 + ty + j * 8) * QKV_LD + 2560 + c0 + tx];
  __syncthreads();
#pragma unroll
  for (int j = 0; j < 4; ++j) {
    int c = c0 + ty + j * 8;              // V column -> (g,d)
    int rr = r0 + tx;                     // source row -> (b,s)
    int b = rr >> 11, s = rr & (SS - 1), g = c >> 6, d = c & 63;
    vt[(size_t)((((b << 3) + g) << 6) + d) * SS + s] = tt[tx][ty + j * 8];
  }
}

// ---------------------------------------------------------------------------
// C[M][N] = A[M][K] @ BT[N][K]^T   (bf16 in, fp32 acc), lda = full K.
// 128x128 tile, BK=64, 4 waves (2x2 of 64x64), global_load_lds w/ swizzled source.
// XCD-aware bijective block swizzle (requires gridDim.x*gridDim.y % 8 == 0).
// Split-K via blockIdx.z: slice z covers k in [z*ksl, z*ksl+ksl).
// Cf!=null: fp32 atomic-accumulate out (+bias from z==0). else bf16 plain store.
__global__ __launch_bounds__(256) void gemm_bt(const u16* __restrict__ A, const u16* __restrict__ BT,
                                               int lda, int ksl,
                                               u16* __restrict__ Cb, float* __restrict__ Cf,
                                               const float* __restrict__ bias, int ldc) {
  __shared__ alignas(16) u16 lds[2 * 128 * 64];
  u16* Al = lds;
  u16* Bl = lds + 128 * 64;
  const int t = threadIdx.x, w = t >> 6, lane = t & 63;
  // XCD swizzle: same-XCD blocks (flat%8 equal) get consecutive tile ids
  const int gx = gridDim.x, nxy = gx * gridDim.y;
  int xy = blockIdx.y * gx + blockIdx.x;
  xy = (xy & 7) * (nxy >> 3) + (xy >> 3);
  const int n0 = (xy % gx) << 7, m0 = (xy / gx) << 7;
  const int kbeg = blockIdx.z * ksl, kend = kbeg + ksl;
  const int wm = (w >> 1) << 6, wn = (w & 1) << 6;
  f32x4 acc[4][4] = {};

  for (int k0 = kbeg; k0 < kend; k0 += 64) {
#pragma unroll
    for (int i = 0; i < 4; ++i) {
      int o = (i << 12) + (w << 10) + (lane << 4);      // byte offset in 16KB tile
      int row = o >> 7;
      int cs = ((((o >> 4) & 7) ^ (row & 7)) << 4);     // pre-swizzled source block
      gload16((const char*)A + (((size_t)(m0 + row) * lda + k0) << 1) + cs, (char*)Al + o);
      gload16((const char*)BT + (((size_t)(n0 + row) * lda + k0) << 1) + cs, (char*)Bl + o);
    }
    __syncthreads();
#pragma unroll
    for (int kk = 0; kk < 64; kk += 32) {
      const int c = (kk >> 3) + (lane >> 4);
      s16x8 af[4], bfr[4];
#pragma unroll
      for (int mi = 0; mi < 4; ++mi) af[mi] = lds_frag(Al, wm + (mi << 4) + (lane & 15), c);
#pragma unroll
      for (int ni = 0; ni < 4; ++ni) bfr[ni] = lds_frag(Bl, wn + (ni << 4) + (lane & 15), c);
#pragma unroll
      for (int mi = 0; mi < 4; ++mi)
#pragma unroll
        for (int ni = 0; ni < 4; ++ni)
          acc[mi][ni] = MFMA(af[mi], bfr[ni], acc[mi][ni]);
    }
    __syncthreads();
  }

  const int rbase = m0 + wm + ((lane >> 4) << 2);
  const int cbase = n0 + wn + (lane & 15);
  if (Cf != nullptr) {
    const bool addb = (bias != nullptr) && (blockIdx.z == 0);
#pragma unroll
    for (int mi = 0; mi < 4; ++mi)
#pragma unroll
      for (int ni = 0; ni < 4; ++ni) {
        int col = cbase + (ni << 4);
        float bv = addb ? bias[col] : 0.f;
#pragma unroll
        for (int r = 0; r < 4; ++r)
          unsafeAtomicAdd(&Cf[(size_t)(rbase + (mi << 4) + r) * ldc + col], acc[mi][ni][r] + bv);
      }
  } else {
#pragma unroll
    for (int mi = 0; mi < 4; ++mi)
#pragma unroll
      for (int ni = 0; ni < 4; ++ni) {
        int col = cbase + (ni << 4);
#pragma unroll
        for (int r = 0; r < 4; ++r)
          Cb[(size_t)(rbase + (mi << 4) + r) * ldc + col] = f2bf(acc[mi][ni][r]);
      }
  }
}

// ---------------------------------------------------------------------------
// Flash attention v6: SWAPPED-OPERAND QK^T (S^T = mfma(K,Q)) so each lane owns
// one q-row: scalar m/lp/alpha, lane-local defer check, k-contiguous P rows
// (4x ds_write_b64 instead of 16x ds_write_b16), PV = mfma(V^T, P^T) -> O^T.
// Q pre-scaled by SCL in rope_k. Reg-staged pipeline + balanced LPT kept.
__global__ __launch_bounds__(256) void attn_k(const u16* __restrict__ qkv, const u16* __restrict__ vt,
                                              u16* __restrict__ ctx) {
  __shared__ alignas(16) u16 sK[64 * 64];
  __shared__ alignas(16) u16 sV[64 * 64];
  __shared__ alignas(16) u16 sP[4][16 * 64];
  const int bid = blockIdx.x;
  const int qt = 31 - (bid >> 6);                 // balanced + LPT
  const int h = bid & 31, b = (bid >> 5) & 1;
  const int q0 = qt << 6, g = h >> 2;
  const int t = threadIdx.x, w = t >> 6, lane = t & 63;
  const int q_l = lane & 15, gh = lane >> 4;

  // staging geometry: chunk i in 0..1, row = (i<<5) + (w<<3) + (lane>>3), blk = lane&7.
  const int srow = (w << 3) + (lane >> 3);        // row within chunk 0 (0..31)
  const int blk = lane & 7;                       // 16B block within 64-u16 row
  const int lw0 = (srow << 6) + ((blk ^ (lane >> 3)) << 3);   // row&7 == lane>>3
  const u16* kg = qkv + (size_t)((b << 11) + srow) * QKV_LD + 2048 + (g << 6) + (blk << 3);
  const u16* vg = vt + (size_t)((((b << 3) + g) << 6) + srow) * SS + (blk << 3);

  // Q fragment (B-frag for swapped QK: lane holds Q[q=lane&15][d=8*gh+e])
  const int qrow = (b << 11) + q0 + (w << 4) + q_l;
  const u16* qptr = qkv + (size_t)qrow * QKV_LD + (h << 6) + (gh << 3);
  s16x8 qa0 = *(const s16x8*)qptr;
  s16x8 qa1 = *(const s16x8*)(qptr + 32);

  f32x4 o[4] = {};
  float m1 = -INFINITY, lp1 = 0.f;
  const int myq = q0 + (w << 4) + q_l;            // this lane's q row

  // prologue: tile 0 regs -> LDS -> barrier
  s16x8 kr[2], vr[2];
#pragma unroll
  for (int i = 0; i < 2; ++i) {
    kr[i] = *(const s16x8*)(kg + (size_t)(i << 5) * QKV_LD);
    vr[i] = *(const s16x8*)(vg + (size_t)(i << 5) * SS);
  }
#pragma unroll
  for (int i = 0; i < 2; ++i) {
    *(s16x8*)(sK + lw0 + (i << 11)) = kr[i];
    *(s16x8*)(sV + lw0 + (i << 11)) = vr[i];
  }
  __syncthreads();

  for (int kt_i = 0; kt_i <= qt; ++kt_i) {
    const int k0 = kt_i << 6;
    // issue next-tile global loads early; latency hides under this tile's compute
    if (kt_i < qt) {
      const int kn = k0 + 64;
#pragma unroll
      for (int i = 0; i < 2; ++i) {
        kr[i] = *(const s16x8*)(kg + (size_t)(kn + (i << 5)) * QKV_LD);
        vr[i] = *(const s16x8*)(vg + (size_t)(i << 5) * SS + kn);
      }
    }

    // S^T = K Q^T (64k x 16q per wave); lane: q = lane&15, k = nc*16 + gh*4 + r
    f32x4 sacc[4];
    __builtin_amdgcn_s_setprio(1);
#pragma unroll
    for (int nc = 0; nc < 4; ++nc) {
      f32x4 a = {};
      a = MFMA(lds_frag(sK, (nc << 4) + q_l, gh), qa0, a);
      a = MFMA(lds_frag(sK, (nc << 4) + q_l, 4 + gh), qa1, a);
      sacc[nc] = a;
    }
    __builtin_amdgcn_s_setprio(0);

    // causal mask on the diagonal tile only (Q already carries the scale)
    float pv[4][4];
    if (kt_i == qt) {
#pragma unroll
      for (int nc = 0; nc < 4; ++nc) {
        int kb = k0 + (nc << 4) + (gh << 2);
#pragma unroll
        for (int r = 0; r < 4; ++r) {
          float v = sacc[nc][r];
          if (kb + r > myq) v = -INFINITY;
          pv[nc][r] = v;
        }
      }
    } else {
#pragma unroll
      for (int nc = 0; nc < 4; ++nc)
#pragma unroll
        for (int r = 0; r < 4; ++r)
          pv[nc][r] = sacc[nc][r];
    }

    // lane-local tile max + defer-max check (scalar m per lane)
    float tmax = pv[0][0];
#pragma unroll
    for (int nc = 0; nc < 4; ++nc)
#pragma unroll
      for (int r = 0; r < 4; ++r) tmax = fmaxf(tmax, pv[nc][r]);
    if (__any(tmax > m1 + 8.f)) {
      // row max over all 64 k (across the 4 lane-groups), uniform per q
      float rmax = tmax;
      rmax = fmaxf(rmax, __shfl_xor(rmax, 16));
      rmax = fmaxf(rmax, __shfl_xor(rmax, 32));
      float mn = fmaxf(m1, rmax);
      float alpha = exp2f(m1 - mn);
      m1 = mn;
      lp1 *= alpha;
#pragma unroll
      for (int dc = 0; dc < 4; ++dc)
#pragma unroll
        for (int r = 0; r < 4; ++r) o[dc][r] *= alpha;
    }

    // P = exp2(S' - m); per-lane partial l (reduced across groups at the end)
#pragma unroll
    for (int nc = 0; nc < 4; ++nc)
#pragma unroll
      for (int r = 0; r < 4; ++r) {
        float p = exp2f(pv[nc][r] - m1);
        pv[nc][r] = p;
        lp1 += p;
      }

    // P^T -> per-wave LDS [16 q][64 k], k-contiguous: one b64 per nc
    u16* pb = sP[w];
#pragma unroll
    for (int nc = 0; nc < 4; ++nc) {
      u32x2 pw;
      pw[0] = cvtpk(pv[nc][0], pv[nc][1]);
      pw[1] = cvtpk(pv[nc][2], pv[nc][3]);
      int byte = (q_l << 7) + (((((nc << 1) + (gh >> 1)) ^ (q_l & 7)) << 4)) + ((gh & 1) << 3);
      *(u32x2*)((char*)pb + byte) = pw;
    }
    asm volatile("s_waitcnt lgkmcnt(0)" ::: "memory");   // intra-wave P write->read
    __builtin_amdgcn_sched_barrier(0);

    // O^T += V^T P^T  (A = V^T from sV, B = P^T from pb; reads unchanged)
    s16x8 pa0 = lds_frag(pb, q_l, gh);
    s16x8 pa1 = lds_frag(pb, q_l, 4 + gh);
    __builtin_amdgcn_s_setprio(1);
#pragma unroll
    for (int dc = 0; dc < 4; ++dc) {
      o[dc] = MFMA(lds_frag(sV, (dc << 4) + q_l, gh), pa0, o[dc]);
      o[dc] = MFMA(lds_frag(sV, (dc << 4) + q_l, 4 + gh), pa1, o[dc]);
    }
    __builtin_amdgcn_s_setprio(0);

    __syncthreads();                 // all waves done reading sK/sV
    if (kt_i < qt) {
#pragma unroll
      for (int i = 0; i < 2; ++i) {
        *(s16x8*)(sK + lw0 + (i << 11)) = kr[i];
        *(s16x8*)(sV + lw0 + (i << 11)) = vr[i];
      }
      __syncthreads();               // staged tile visible to all waves
    }
  }

  // epilogue: l = sum over the 4 lane-groups; ctx row is fixed per lane (q)
  lp1 += __shfl_xor(lp1, 16);
  lp1 += __shfl_xor(lp1, 32);
  float inv = 1.0f / lp1;
  u16* crow = ctx + (size_t)((b << 11) + myq) * DD + (h << 6) + (gh << 2);
#pragma unroll
  for (int dc = 0; dc < 4; ++dc) {
    u32x2 ov;
    ov[0] = cvtpk(o[dc][0] * inv, o[dc][1] * inv);
    ov[1] = cvtpk(o[dc][2] * inv, o[dc][3] * inv);
    *(u32x2*)(crow + (dc << 4)) = ov;
  }
}

// ---------------------------------------------------------------------------
extern "C" void kernel_launch(void* const* d_in, const int* in_sizes, int n_in,
                              void* d_out, int out_size, void* d_ws, size_t ws_size,
                              hipStream_t stream) {
  const float* x  = (const float*)d_in[0];
  const float* Wq = (const float*)d_in[1];
  const float* Wk = (const float*)d_in[2];
  const float* Wv = (const float*)d_in[3];
  const float* Wo = (const float*)d_in[4];
  const float* bo = (const float*)d_in[5];
  const float* fc = (const float*)d_in[6];
  const float* fs = (const float*)d_in[7];
  float* out = (float*)d_out;

  // workspace layout (u16 units), 58.7 MB total:
  u16* ws   = (u16*)d_ws;
  u16* xb   = ws;                      // 8,388,608  (x bf16; reused as ctx)
  u16* wT   = xb + 8388608;            // 6,291,456  (W_qkv^T; reused as W_o^T)
  u16* qkv  = wT + 6291456;            // 12,582,912 (Q|K|V, ld 3072)
  u16* vt   = qkv + 12582912;          // 2,097,152  (V^T per (b,g): [64][2048])
  u16* ctx  = xb;
  u16* woT  = wT;

  dim3 b32(32, 8, 1);

  // 1. casts / transposes of weights + x
  cast_bf<<<8192, 256, 0, stream>>>(x, xb);
  tcast<<<dim3(64, 64), b32, 0, stream>>>(Wq, 2048, wT, 2048);
  tcast<<<dim3(16, 64), b32, 0, stream>>>(Wk, 512, wT + (size_t)2048 * 2048, 2048);
  tcast<<<dim3(16, 64), b32, 0, stream>>>(Wv, 512, wT + (size_t)2560 * 2048, 2048);

  // 2. fused QKV projection: [4096][2048] @ [3072][2048]^T -> qkv bf16 (z=1, full K)
  gemm_bt<<<dim3(24, 32, 1), 256, 0, stream>>>(xb, wT, 2048, 2048, qkv, nullptr, nullptr, QKV_LD);

  // 3. W_o^T; zero d_out for the split-K atomic accumulation
  tcast<<<dim3(64, 64), b32, 0, stream>>>(Wo, 2048, woT, 2048);
  zero_f4<<<8192, 256, 0, stream>>>(out);

  // 4. RoPE on Q,K (Q pre-scaled); transpose V
  rope_k<<<20480, 256, 0, stream>>>(qkv, fc, fs);
  transpose_v<<<dim3(16, 128), b32, 0, stream>>>(qkv, vt);

  // 5. flash attention -> ctx bf16 [4096][2048]
  attn_k<<<2048, 256, 0, stream>>>(qkv, vt, ctx);

  // 6. output projection + bias -> fp32 d_out, split-K x2 (K slices of 1024)
  gemm_bt<<<dim3(16, 32, 2), 256, 0, stream>>>(ctx, woT, 2048, 1024, nullptr, out, bo, 2048);
}

// Round 9
// 216.647 us; speedup vs baseline: 1.2503x; 1.2503x over previous
//
#include <hip/hip_runtime.h>
#include <hip/hip_bf16.h>

// Problem constants: B=2, S=2048, D=2048, H=32, KVH=8, HD=64, N_REP=4
#define BB 2
#define SS 2048
#define DD 2048
#define HH 32
#define KVH 8
#define HD 64
#define QKV_LD 3072   // Q(2048) | K(512) | V(512)

typedef unsigned short u16;
typedef unsigned int u32;
typedef __attribute__((ext_vector_type(8))) short s16x8;   // bf16x8 MFMA fragment (4 VGPRs)
typedef __attribute__((ext_vector_type(4))) float f32x4;   // MFMA accumulator
typedef __attribute__((ext_vector_type(4))) u16 u16x4;
typedef __attribute__((ext_vector_type(2))) u32 u32x2;

#define MFMA(a, b, c) __builtin_amdgcn_mfma_f32_16x16x32_bf16((a), (b), (c), 0, 0, 0)

__device__ __forceinline__ u16 f2bf(float f) {
  union { float f; u32 u; } x; x.f = f;
  u32 r = x.u + 0x7fffu + ((x.u >> 16) & 1u);  // round-to-nearest-even
  return (u16)(r >> 16);
}
__device__ __forceinline__ float bf2f(u32 u) {
  union { u32 u; float f; } x; x.u = u << 16;
  return x.f;
}
// HW packed f32x2 -> bf16x2 (RTNE), lo=a, hi=b
__device__ __forceinline__ u32 cvtpk(float a, float b) {
  u32 r;
  asm("v_cvt_pk_bf16_f32 %0, %1, %2" : "=v"(r) : "v"(a), "v"(b));
  return r;
}

// async global->LDS, 16B per lane. dest must be (wave-uniform base + lane*16).
__device__ __forceinline__ void gload16(const void* g, void* l) {
  __builtin_amdgcn_global_load_lds((const __attribute__((address_space(1))) unsigned int*)g,
                                   (__attribute__((address_space(3))) unsigned int*)l, 16, 0, 0);
}

// Read one bf16x8 MFMA fragment from a [rows][64] bf16 LDS tile with the
// G4 XOR swizzle (16B block index ^= row&7). c = 16B-block index (k/8).
__device__ __forceinline__ s16x8 lds_frag(const u16* base, int row, int c) {
  return *(const s16x8*)(base + (row << 6) + (((c ^ (row & 7)) << 3)));
}

// ---------------------------------------------------------------------------
// cast fp32 -> bf16, 4 elems/thread, exact grid
__global__ void cast_bf(const float* __restrict__ s, u16* __restrict__ d) {
  int i = blockIdx.x * 256 + threadIdx.x;
  float4 v = ((const float4*)s)[i];
  u16x4 o;
  o[0] = f2bf(v.x); o[1] = f2bf(v.y); o[2] = f2bf(v.z); o[3] = f2bf(v.w);
  ((u16x4*)d)[i] = o;
}

// transpose-cast: dst[c*dld + r] = bf16(src[r*scols + c]); grid (scols/32, srows/32), block (32,8)
__global__ void tcast(const float* __restrict__ src, int scols, u16* __restrict__ dst, int dld) {
  __shared__ float tt[32][33];
  int c0 = blockIdx.x << 5, r0 = blockIdx.y << 5;
  int tx = threadIdx.x, ty = threadIdx.y;
#pragma unroll
  for (int j = 0; j < 4; ++j)
    tt[ty + j * 8][tx] = src[(size_t)(r0 + ty + j * 8) * scols + c0 + tx];
  __syncthreads();
#pragma unroll
  for (int j = 0; j < 4; ++j)
    dst[(size_t)(c0 + ty + j * 8) * dld + r0 + tx] = f2bf(tt[tx][ty + j * 8]);
}

// RoPE in-place on Q cols [0,2048) and K cols [2048,2560) of qkv [4096][3072].
// Q additionally pre-scaled by 1/sqrt(HD)*log2(e) (folded attention scale).
__global__ void rope_k(u16* __restrict__ qkv, const float* __restrict__ fc, const float* __restrict__ fs) {
  const float SCLQ = 0.125f * 1.44269504f;
  int idx = blockIdx.x * 256 + threadIdx.x;          // 4096*1280 total
  int row = idx / 1280;
  int p = idx - row * 1280;
  int s = row & (SS - 1);
  int col, i;
  float sc;
  if (p < 1024) { col = p << 1; i = p & 31; sc = SCLQ; }
  else { int pk = p - 1024; col = 2048 + (pk << 1); i = pk & 31; sc = 1.0f; }
  size_t base = (size_t)row * QKV_LD + col;
  u32 v = *(const u32*)(qkv + base);
  float t1 = bf2f(v & 0xffffu), t2 = bf2f(v >> 16);
  float c = fc[s * 32 + i], sn = fs[s * 32 + i];
  float r1 = (t1 * c - t2 * sn) * sc;
  float r2 = (t1 * sn + t2 * c) * sc;
  *(u32*)(qkv + base) = (u32)f2bf(r1) | ((u32)f2bf(r2) << 16);
}

// V part of qkv (cols [2560,3072)) -> vt[((b*8+g)*64 + d)*2048 + s]
__global__ void transpose_v(const u16* __restrict__ qkv, u16* __restrict__ vt) {
  __shared__ u16 tt[32][33];
  int c0 = blockIdx.x << 5, r0 = blockIdx.y << 5;   // c0: V col, r0: b*S+s row
  int tx = threadIdx.x, ty = threadIdx.y;
#pragma unroll
  for (int j = 0; j < 4; ++j)
    tt[ty + j * 8][tx] = qkv[(size_t)(r0 + ty + j * 8) * QKV_LD + 2560 + c0 + tx];
  __syncthreads();
#pragma unroll
  for (int j = 0; j < 4; ++j) {
    int c = c0 + ty + j * 8;              // V column -> (g,d)
    int rr = r0 + tx;                     // source row -> (b,s)
    int b = rr >> 11, s = rr & (SS - 1), g = c >> 6, d = c & 63;
    vt[(size_t)((((b << 3) + g) << 6) + d) * SS + s] = tt[tx][ty + j * 8];
  }
}

// ---------------------------------------------------------------------------
// C[M][N] = A[M][K] @ BT[N][K]^T   (bf16 in, fp32 acc), lda == K.
// 128x128 tile, BK=64, EIGHT waves (2m x 4n, each 64x32), 512 threads.
// Same 2-barrier structure as the verified 4-wave version; more waves/CU
// hide the barrier drain. global_load_lds w/ swizzled source.
// Cf!=null: fp32 out + bias. else bf16 out.
__global__ __launch_bounds__(512) void gemm_bt(const u16* __restrict__ A, const u16* __restrict__ BT,
                                               int K, u16* __restrict__ Cb, float* __restrict__ Cf,
                                               const float* __restrict__ bias, int ldc) {
  __shared__ alignas(16) u16 lds[2 * 128 * 64];
  u16* Al = lds;
  u16* Bl = lds + 128 * 64;
  const int t = threadIdx.x, w = t >> 6, lane = t & 63;
  const int q_l = lane & 15, gh = lane >> 4;
  const int m0 = blockIdx.y << 7, n0 = blockIdx.x << 7;
  const int wm = (w >> 2) << 6;        // 0 or 64
  const int wn = (w & 3) << 5;         // 0,32,64,96
  f32x4 acc[4][2] = {};

  for (int k0 = 0; k0 < K; k0 += 64) {
#pragma unroll
    for (int i = 0; i < 2; ++i) {
      int o = (i << 13) + (t << 4);                     // byte offset in 16KB tile
      int row = o >> 7;
      int cs = ((((o >> 4) & 7) ^ (row & 7)) << 4);     // pre-swizzled source block
      gload16((const char*)A + (((size_t)(m0 + row) * K + k0) << 1) + cs, (char*)Al + o);
      gload16((const char*)BT + (((size_t)(n0 + row) * K + k0) << 1) + cs, (char*)Bl + o);
    }
    __syncthreads();
#pragma unroll
    for (int kk = 0; kk < 64; kk += 32) {
      const int c = (kk >> 3) + gh;
      s16x8 af[4], bfr[2];
#pragma unroll
      for (int mi = 0; mi < 4; ++mi) af[mi] = lds_frag(Al, wm + (mi << 4) + q_l, c);
#pragma unroll
      for (int ni = 0; ni < 2; ++ni) bfr[ni] = lds_frag(Bl, wn + (ni << 4) + q_l, c);
#pragma unroll
      for (int mi = 0; mi < 4; ++mi)
#pragma unroll
        for (int ni = 0; ni < 2; ++ni)
          acc[mi][ni] = MFMA(af[mi], bfr[ni], acc[mi][ni]);
    }
    __syncthreads();
  }

  const int rbase = m0 + wm + (gh << 2);
  const int cbase = n0 + wn + q_l;
  if (Cf != nullptr) {
#pragma unroll
    for (int mi = 0; mi < 4; ++mi)
#pragma unroll
      for (int ni = 0; ni < 2; ++ni) {
        int col = cbase + (ni << 4);
        float bv = bias[col];
#pragma unroll
        for (int r = 0; r < 4; ++r)
          Cf[(size_t)(rbase + (mi << 4) + r) * ldc + col] = acc[mi][ni][r] + bv;
      }
  } else {
#pragma unroll
    for (int mi = 0; mi < 4; ++mi)
#pragma unroll
      for (int ni = 0; ni < 2; ++ni) {
        int col = cbase + (ni << 4);
#pragma unroll
        for (int r = 0; r < 4; ++r)
          Cb[(size_t)(rbase + (mi << 4) + r) * ldc + col] = f2bf(acc[mi][ni][r]);
      }
  }
}

// ---------------------------------------------------------------------------
// Flash attention v6: SWAPPED-OPERAND QK^T (S^T = mfma(K,Q)) so each lane owns
// one q-row: scalar m/lp/alpha, lane-local defer check, k-contiguous P rows
// (4x ds_write_b64 instead of 16x ds_write_b16), PV = mfma(V^T, P^T) -> O^T.
// Q pre-scaled by SCL in rope_k. Reg-staged pipeline + balanced LPT kept.
__global__ __launch_bounds__(256) void attn_k(const u16* __restrict__ qkv, const u16* __restrict__ vt,
                                              u16* __restrict__ ctx) {
  __shared__ alignas(16) u16 sK[64 * 64];
  __shared__ alignas(16) u16 sV[64 * 64];
  __shared__ alignas(16) u16 sP[4][16 * 64];
  const int bid = blockIdx.x;
  const int qt = 31 - (bid >> 6);                 // balanced + LPT
  const int h = bid & 31, b = (bid >> 5) & 1;
  const int q0 = qt << 6, g = h >> 2;
  const int t = threadIdx.x, w = t >> 6, lane = t & 63;
  const int q_l = lane & 15, gh = lane >> 4;

  // staging geometry: chunk i in 0..1, row = (i<<5) + (w<<3) + (lane>>3), blk = lane&7.
  const int srow = (w << 3) + (lane >> 3);        // row within chunk 0 (0..31)
  const int blk = lane & 7;                       // 16B block within 64-u16 row
  const int lw0 = (srow << 6) + ((blk ^ (lane >> 3)) << 3);   // row&7 == lane>>3
  const u16* kg = qkv + (size_t)((b << 11) + srow) * QKV_LD + 2048 + (g << 6) + (blk << 3);
  const u16* vg = vt + (size_t)((((b << 3) + g) << 6) + srow) * SS + (blk << 3);

  // Q fragment (B-frag for swapped QK: lane holds Q[q=lane&15][d=8*gh+e])
  const int qrow = (b << 11) + q0 + (w << 4) + q_l;
  const u16* qptr = qkv + (size_t)qrow * QKV_LD + (h << 6) + (gh << 3);
  s16x8 qa0 = *(const s16x8*)qptr;
  s16x8 qa1 = *(const s16x8*)(qptr + 32);

  f32x4 o[4] = {};
  float m1 = -INFINITY, lp1 = 0.f;
  const int myq = q0 + (w << 4) + q_l;            // this lane's q row

  // prologue: tile 0 regs -> LDS -> barrier
  s16x8 kr[2], vr[2];
#pragma unroll
  for (int i = 0; i < 2; ++i) {
    kr[i] = *(const s16x8*)(kg + (size_t)(i << 5) * QKV_LD);
    vr[i] = *(const s16x8*)(vg + (size_t)(i << 5) * SS);
  }
#pragma unroll
  for (int i = 0; i < 2; ++i) {
    *(s16x8*)(sK + lw0 + (i << 11)) = kr[i];
    *(s16x8*)(sV + lw0 + (i << 11)) = vr[i];
  }
  __syncthreads();

  for (int kt_i = 0; kt_i <= qt; ++kt_i) {
    const int k0 = kt_i << 6;
    // issue next-tile global loads early; latency hides under this tile's compute
    if (kt_i < qt) {
      const int kn = k0 + 64;
#pragma unroll
      for (int i = 0; i < 2; ++i) {
        kr[i] = *(const s16x8*)(kg + (size_t)(kn + (i << 5)) * QKV_LD);
        vr[i] = *(const s16x8*)(vg + (size_t)(i << 5) * SS + kn);
      }
    }

    // S^T = K Q^T (64k x 16q per wave); lane: q = lane&15, k = nc*16 + gh*4 + r
    f32x4 sacc[4];
    __builtin_amdgcn_s_setprio(1);
#pragma unroll
    for (int nc = 0; nc < 4; ++nc) {
      f32x4 a = {};
      a = MFMA(lds_frag(sK, (nc << 4) + q_l, gh), qa0, a);
      a = MFMA(lds_frag(sK, (nc << 4) + q_l, 4 + gh), qa1, a);
      sacc[nc] = a;
    }
    __builtin_amdgcn_s_setprio(0);

    // causal mask on the diagonal tile only (Q already carries the scale)
    float pv[4][4];
    if (kt_i == qt) {
#pragma unroll
      for (int nc = 0; nc < 4; ++nc) {
        int kb = k0 + (nc << 4) + (gh << 2);
#pragma unroll
        for (int r = 0; r < 4; ++r) {
          float v = sacc[nc][r];
          if (kb + r > myq) v = -INFINITY;
          pv[nc][r] = v;
        }
      }
    } else {
#pragma unroll
      for (int nc = 0; nc < 4; ++nc)
#pragma unroll
        for (int r = 0; r < 4; ++r)
          pv[nc][r] = sacc[nc][r];
    }

    // lane-local tile max + defer-max check (scalar m per lane)
    float tmax = pv[0][0];
#pragma unroll
    for (int nc = 0; nc < 4; ++nc)
#pragma unroll
      for (int r = 0; r < 4; ++r) tmax = fmaxf(tmax, pv[nc][r]);
    if (__any(tmax > m1 + 8.f)) {
      // row max over all 64 k (across the 4 lane-groups), uniform per q
      float rmax = tmax;
      rmax = fmaxf(rmax, __shfl_xor(rmax, 16));
      rmax = fmaxf(rmax, __shfl_xor(rmax, 32));
      float mn = fmaxf(m1, rmax);
      float alpha = exp2f(m1 - mn);
      m1 = mn;
      lp1 *= alpha;
#pragma unroll
      for (int dc = 0; dc < 4; ++dc)
#pragma unroll
        for (int r = 0; r < 4; ++r) o[dc][r] *= alpha;
    }

    // P = exp2(S' - m); per-lane partial l (reduced across groups at the end)
#pragma unroll
    for (int nc = 0; nc < 4; ++nc)
#pragma unroll
      for (int r = 0; r < 4; ++r) {
        float p = exp2f(pv[nc][r] - m1);
        pv[nc][r] = p;
        lp1 += p;
      }

    // P^T -> per-wave LDS [16 q][64 k], k-contiguous: one b64 per nc
    u16* pb = sP[w];
#pragma unroll
    for (int nc = 0; nc < 4; ++nc) {
      u32x2 pw;
      pw[0] = cvtpk(pv[nc][0], pv[nc][1]);
      pw[1] = cvtpk(pv[nc][2], pv[nc][3]);
      int byte = (q_l << 7) + (((((nc << 1) + (gh >> 1)) ^ (q_l & 7)) << 4)) + ((gh & 1) << 3);
      *(u32x2*)((char*)pb + byte) = pw;
    }
    asm volatile("s_waitcnt lgkmcnt(0)" ::: "memory");   // intra-wave P write->read
    __builtin_amdgcn_sched_barrier(0);

    // O^T += V^T P^T  (A = V^T from sV, B = P^T from pb; reads unchanged)
    s16x8 pa0 = lds_frag(pb, q_l, gh);
    s16x8 pa1 = lds_frag(pb, q_l, 4 + gh);
    __builtin_amdgcn_s_setprio(1);
#pragma unroll
    for (int dc = 0; dc < 4; ++dc) {
      o[dc] = MFMA(lds_frag(sV, (dc << 4) + q_l, gh), pa0, o[dc]);
      o[dc] = MFMA(lds_frag(sV, (dc << 4) + q_l, 4 + gh), pa1, o[dc]);
    }
    __builtin_amdgcn_s_setprio(0);

    __syncthreads();                 // all waves done reading sK/sV
    if (kt_i < qt) {
#pragma unroll
      for (int i = 0; i < 2; ++i) {
        *(s16x8*)(sK + lw0 + (i << 11)) = kr[i];
        *(s16x8*)(sV + lw0 + (i << 11)) = vr[i];
      }
      __syncthreads();               // staged tile visible to all waves
    }
  }

  // epilogue: l = sum over the 4 lane-groups; ctx row is fixed per lane (q)
  lp1 += __shfl_xor(lp1, 16);
  lp1 += __shfl_xor(lp1, 32);
  float inv = 1.0f / lp1;
  u16* crow = ctx + (size_t)((b << 11) + myq) * DD + (h << 6) + (gh << 2);
#pragma unroll
  for (int dc = 0; dc < 4; ++dc) {
    u32x2 ov;
    ov[0] = cvtpk(o[dc][0] * inv, o[dc][1] * inv);
    ov[1] = cvtpk(o[dc][2] * inv, o[dc][3] * inv);
    *(u32x2*)(crow + (dc << 4)) = ov;
  }
}

// ---------------------------------------------------------------------------
extern "C" void kernel_launch(void* const* d_in, const int* in_sizes, int n_in,
                              void* d_out, int out_size, void* d_ws, size_t ws_size,
                              hipStream_t stream) {
  const float* x  = (const float*)d_in[0];
  const float* Wq = (const float*)d_in[1];
  const float* Wk = (const float*)d_in[2];
  const float* Wv = (const float*)d_in[3];
  const float* Wo = (const float*)d_in[4];
  const float* bo = (const float*)d_in[5];
  const float* fc = (const float*)d_in[6];
  const float* fs = (const float*)d_in[7];
  float* out = (float*)d_out;

  // workspace layout (u16 units), 58.7 MB total:
  u16* ws   = (u16*)d_ws;
  u16* xb   = ws;                      // 8,388,608  (x bf16; reused as ctx)
  u16* wT   = xb + 8388608;            // 6,291,456  (W_qkv^T; reused as W_o^T)
  u16* qkv  = wT + 6291456;            // 12,582,912 (Q|K|V, ld 3072)
  u16* vt   = qkv + 12582912;          // 2,097,152  (V^T per (b,g): [64][2048])
  u16* ctx  = xb;
  u16* woT  = wT;

  dim3 b32(32, 8, 1);

  // 1. casts / transposes of weights + x
  cast_bf<<<8192, 256, 0, stream>>>(x, xb);
  tcast<<<dim3(64, 64), b32, 0, stream>>>(Wq, 2048, wT, 2048);
  tcast<<<dim3(16, 64), b32, 0, stream>>>(Wk, 512, wT + (size_t)2048 * 2048, 2048);
  tcast<<<dim3(16, 64), b32, 0, stream>>>(Wv, 512, wT + (size_t)2560 * 2048, 2048);

  // 2. fused QKV projection: [4096][2048] @ [3072][2048]^T -> qkv bf16
  gemm_bt<<<dim3(24, 32), 512, 0, stream>>>(xb, wT, 2048, qkv, nullptr, nullptr, QKV_LD);

  // 3. W_o^T
  tcast<<<dim3(64, 64), b32, 0, stream>>>(Wo, 2048, woT, 2048);

  // 4. RoPE on Q,K (Q pre-scaled); transpose V
  rope_k<<<20480, 256, 0, stream>>>(qkv, fc, fs);
  transpose_v<<<dim3(16, 128), b32, 0, stream>>>(qkv, vt);

  // 5. flash attention -> ctx bf16 [4096][2048]
  attn_k<<<2048, 256, 0, stream>>>(qkv, vt, ctx);

  // 6. output projection + bias -> fp32 d_out
  gemm_bt<<<dim3(16, 32), 512, 0, stream>>>(ctx, woT, 2048, nullptr, out, bo, 2048);
}